// Round 7
// baseline (1113.739 us; speedup 1.0000x reference)
//
#include <hip/hip_runtime.h>
#include <hip/hip_bf16.h>
#include <math.h>

typedef __hip_bfloat16 bf16;
typedef __attribute__((ext_vector_type(8))) short short8v;   // 8 bf16 (4 VGPRs)
typedef __attribute__((ext_vector_type(4))) float float4v;   // mfma acc

#define NODES 20000
#define EDG   400000
#define ETOT  (EDG + NODES)
#define GB    200
#define HEADS 10
#define FD    78
#define HIDD  780
#define SEQL  1000
#define VOCS  26
#define EMBD  128
#define NFC   32
#define KSZ   8
#define COUT  993
#define KFXT  (NFC * COUT)

#define MPAD  20096   // 157*128
#define NPADB 896     // 7*128
#define KP1   96      // K=78 padded to 3*32
#define KP2   800     // K=780 padded to 25*32
#define HP    784     // padded h/h2 row stride (196*4) for uint2 gathers

// diag[0] bits: 1=CSR structural, 2=gat logits NaN, 8=gat acc NaN, 16=gcn acc NaN,
// 4096=conv NaN, 8192=idx OOB
// diag[1]: 0 = inputs are bf16, 1 = inputs are fp32

__device__ __forceinline__ float us2f(unsigned short u) {
  unsigned int i = ((unsigned int)u) << 16; float f; __builtin_memcpy(&f, &i, 4); return f;
}
__device__ __forceinline__ float b2f(bf16 v) { return __bfloat162float(v); }
__device__ __forceinline__ float ldany(const void* p, size_t i, int m) {
  if (m) return ((const float*)p)[i];
  return b2f(((const bf16*)p)[i]);
}
__device__ __forceinline__ bool nanf_(float v) { return v != v; }

// ---------- runtime dtype detection on x
__global__ void k_detect(const void* x, int* diag) {
  int t = threadIdx.x;
  const unsigned short* u = (const unsigned short*)x;
  int hit = 0;
  for (int i = t; i < 4096; i += 256) {
    float v = us2f(u[i]);
    if (nanf_(v) || fabsf(v) > 1e6f) hit = 1;
  }
  if (hit) diag[1] = 1;  // benign race: all writers store 1
}

// ---------- pad/convert x -> xpad[MPAD][KP1] bf16 (zeros in pads)
__global__ void k_pad_x(const void* x, bf16* xpad, const int* diag) {
  int idx = blockIdx.x * 256 + threadIdx.x;
  if (idx >= MPAD * KP1) return;
  int mode = diag[1];
  int m = idx / KP1, k = idx % KP1;
  float v = (m < NODES && k < FD) ? ldany(x, (size_t)m * FD + k, mode) : 0.f;
  xpad[idx] = __float2bfloat16(v);
}

// ---------- transpose gat_W [78][780] -> gatWt[NPADB][KP1]
__global__ void k_tr_gatw(const void* gw, bf16* Wt, const int* diag) {
  int idx = blockIdx.x * 256 + threadIdx.x;
  if (idx >= NPADB * KP1) return;
  int mode = diag[1];
  int n = idx / KP1, k = idx % KP1;
  float v = (n < HIDD && k < FD) ? ldany(gw, (size_t)k * HIDD + n, mode) : 0.f;
  Wt[idx] = __float2bfloat16(v);
}

// ---------- transpose gcn_W [780][780] -> gcnWt[NPADB][KP2]
__global__ void k_tr_gcnw(const void* gw, bf16* Wt, const int* diag) {
  int idx = blockIdx.x * 256 + threadIdx.x;
  if (idx >= NPADB * KP2) return;
  int mode = diag[1];
  int n = idx / KP2, k = idx % KP2;
  float v = (n < HIDD && k < HIDD) ? ldany(gw, (size_t)k * HIDD + n, mode) : 0.f;
  Wt[idx] = __float2bfloat16(v);
}

// ---------- zero pad rows of x1p (rows 20000..20095)
__global__ void k_zero_x1pad(bf16* x1p) {
  int i = blockIdx.x * 256 + threadIdx.x;
  if (i < (MPAD - NODES) * KP2)
    x1p[(size_t)NODES * KP2 + i] = __float2bfloat16(0.f);
}

// ---------- MFMA bf16 GEMM: C[gm*ldc+gn] = A[M x Kp (lda)] @ Bt[n][k] (ldb)
// Stores cols gn < Ncap (cols >= logical N are exact zeros from zero-padded B rows).
#define MT 128
#define NT 128
#define BK 32
#define LP 40   // LDS row stride (bf16): 80B rows -> 16B-aligned b128
__global__ __launch_bounds__(256) void k_gemm_mfma(const bf16* A, int lda,
                                                   const bf16* Bt, int ldb,
                                                   bf16* C, int ldc, int Ncap,
                                                   int M, int Kp) {
  __shared__ __align__(16) bf16 As[MT * LP];
  __shared__ __align__(16) bf16 Bs[NT * LP];
  int t = threadIdx.x;
  int lane = t & 63, w = t >> 6;
  int wr = (w >> 1) * 64, wc = (w & 1) * 64;
  int quad = lane >> 4, mr = lane & 15;
  int m0 = blockIdx.y * MT, n0 = blockIdx.x * NT;
  float4v acc[4][4];
#pragma unroll
  for (int i = 0; i < 4; ++i)
#pragma unroll
    for (int j = 0; j < 4; ++j) acc[i][j] = (float4v){0.f, 0.f, 0.f, 0.f};

  for (int kc = 0; kc < Kp; kc += BK) {
#pragma unroll
    for (int i = 0; i < 4; ++i) {
      int c = t + i * 256;
      int row = c >> 3, col = (c & 7) * 4;
      *(uint2*)&As[row * LP + col] =
          *(const uint2*)&A[(size_t)(m0 + row) * lda + kc + col];
      *(uint2*)&Bs[row * LP + col] =
          *(const uint2*)&Bt[(size_t)(n0 + row) * ldb + kc + col];
    }
    __syncthreads();
    short8v af[4], bfr[4];
#pragma unroll
    for (int i = 0; i < 4; ++i)
      af[i] = *(const short8v*)&As[(wr + i * 16 + mr) * LP + quad * 8];
#pragma unroll
    for (int j = 0; j < 4; ++j)
      bfr[j] = *(const short8v*)&Bs[(wc + j * 16 + mr) * LP + quad * 8];
#pragma unroll
    for (int i = 0; i < 4; ++i)
#pragma unroll
      for (int j = 0; j < 4; ++j)
        acc[i][j] = __builtin_amdgcn_mfma_f32_16x16x32_bf16(af[i], bfr[j], acc[i][j], 0, 0, 0);
    __syncthreads();
  }
#pragma unroll
  for (int i = 0; i < 4; ++i) {
    int gm0 = m0 + wr + i * 16 + quad * 4;
#pragma unroll
    for (int j = 0; j < 4; ++j) {
      int gn = n0 + wc + j * 16 + mr;
      if (gn >= Ncap) continue;
#pragma unroll
      for (int r = 0; r < 4; ++r) {
        int gm = gm0 + r;
        if (gm < M) C[(size_t)gm * ldc + gn] = __float2bfloat16(acc[i][j][r]);
      }
    }
  }
}

// ---------- MFMA small-M dense layer: out[M,N] (+)= A[M,K] @ B[K,N]
#define MLP_NT 64
#define MLP_BK 32
#define MLP_MT 208
#define MLP_LP 40
__global__ __launch_bounds__(256) void k_mlp_mfma(const void* A, int lda, const void* Bw,
                                                  const void* bias, float* out, int ostride,
                                                  int ooff, int M, int Nn, int K,
                                                  int ksplit, int aRelu, int aBf16,
                                                  const int* diag) {
  __shared__ __align__(16) bf16 As[MLP_MT * MLP_LP];
  __shared__ __align__(16) bf16 Bs[MLP_NT * MLP_LP];
  int mode = diag[1];
  int t = threadIdx.x;
  int lane = t & 63, w = t >> 6;
  int quad = lane >> 4, mr = lane & 15;
  int n0 = blockIdx.x * MLP_NT;
  int kz = blockIdx.y;
  int nchunks = (K + MLP_BK - 1) / MLP_BK;
  int cpk = (nchunks + ksplit - 1) / ksplit;
  int c0 = kz * cpk, c1 = c0 + cpk;
  if (c1 > nchunks) c1 = nchunks;
  float4v acc[13];
#pragma unroll
  for (int i = 0; i < 13; ++i) acc[i] = (float4v){0.f, 0.f, 0.f, 0.f};

  for (int c = c0; c < c1; ++c) {
    int k0 = c * MLP_BK;
    if (aBf16) {
      const bf16* Ab = (const bf16*)A;
      for (int e = t; e < MLP_MT * 4; e += 256) {
        int row = e >> 2, c8 = (e & 3) * 8;
        int gk = k0 + c8;
        if (row < M && gk + 7 < K) {
          *(uint4*)&As[row * MLP_LP + c8] = *(const uint4*)&Ab[(size_t)row * lda + gk];
        } else {
#pragma unroll
          for (int kk = 0; kk < 8; ++kk) {
            float v = (row < M && gk + kk < K) ? b2f(Ab[(size_t)row * lda + gk + kk]) : 0.f;
            As[row * MLP_LP + c8 + kk] = __float2bfloat16(v);
          }
        }
      }
    } else {
      const float* Af = (const float*)A;
      for (int e = t; e < MLP_MT * 8; e += 256) {
        int row = e >> 3, c4 = (e & 7) * 4;
        int gk = k0 + c4;
        float4 v4 = {0.f, 0.f, 0.f, 0.f};
        if (row < M) {
          if (gk + 3 < K) {
            v4 = *(const float4*)&Af[(size_t)row * lda + gk];
          } else {
            v4.x = (gk + 0 < K) ? Af[(size_t)row * lda + gk + 0] : 0.f;
            v4.y = (gk + 1 < K) ? Af[(size_t)row * lda + gk + 1] : 0.f;
            v4.z = (gk + 2 < K) ? Af[(size_t)row * lda + gk + 2] : 0.f;
            v4.w = (gk + 3 < K) ? Af[(size_t)row * lda + gk + 3] : 0.f;
          }
        }
        if (aRelu) {
          v4.x = fmaxf(v4.x, 0.f); v4.y = fmaxf(v4.y, 0.f);
          v4.z = fmaxf(v4.z, 0.f); v4.w = fmaxf(v4.w, 0.f);
        }
        bf16* dst = &As[row * MLP_LP + c4];
        dst[0] = __float2bfloat16(v4.x); dst[1] = __float2bfloat16(v4.y);
        dst[2] = __float2bfloat16(v4.z); dst[3] = __float2bfloat16(v4.w);
      }
    }
    for (int e = t; e < MLP_NT * MLP_BK; e += 256) {
      int k = e >> 6, col = e & 63;
      int gk = k0 + k, gn = n0 + col;
      float v = (gn < Nn && gk < K) ? ldany(Bw, (size_t)gk * Nn + gn, mode) : 0.f;
      Bs[col * MLP_LP + k] = __float2bfloat16(v);
    }
    __syncthreads();
    short8v bf = *(const short8v*)&Bs[(w * 16 + mr) * MLP_LP + quad * 8];
#pragma unroll
    for (int i = 0; i < 13; ++i) {
      short8v af = *(const short8v*)&As[(i * 16 + mr) * MLP_LP + quad * 8];
      acc[i] = __builtin_amdgcn_mfma_f32_16x16x32_bf16(af, bf, acc[i], 0, 0, 0);
    }
    __syncthreads();
  }
  int gn = n0 + w * 16 + mr;
  if (gn >= Nn) return;
  float bs = (kz == 0) ? ldany(bias, gn, mode) : 0.f;
#pragma unroll
  for (int i = 0; i < 13; ++i) {
    int gm0 = i * 16 + quad * 4;
#pragma unroll
    for (int r = 0; r < 4; ++r) {
      int gm = gm0 + r;
      if (gm >= M) break;
      float v = acc[i][r] + bs;
      float* op = &out[(size_t)gm * ostride + ooff + gn];
      if (ksplit == 1) *op = v;
      else atomicAdd(op, v);
    }
  }
}

// ---------- fold gat_a: Ws[k][hd] = sum_f W[k,hd*F+f]*a_src[hd,f]
__global__ void k_prep_ws(const void* gat_W, const void* a_src, const void* a_dst,
                          float* Ws, float* Wd, const int* diag) {
  int idx = blockIdx.x * 256 + threadIdx.x;
  if (idx >= FD * HEADS) return;
  int mode = diag[1];
  int k = idx / HEADS, hd = idx % HEADS;
  float s = 0.f, d = 0.f;
  for (int f = 0; f < FD; ++f) {
    float w = ldany(gat_W, (size_t)k * HIDD + hd * FD + f, mode);
    s += w * ldany(a_src, (size_t)hd * FD + f, mode);
    d += w * ldany(a_dst, (size_t)hd * FD + f, mode);
  }
  Ws[k * HEADS + hd] = s;
  Wd[k * HEADS + hd] = d;
}

// ---------- conv LUT: Mtab[(o*KSZ+k)*VOCS+v] = sum_i emb[v,i]*cW[o,i,k]
__global__ void k_prep_mtab(const void* emb, const void* cW, float* Mtab, const int* diag) {
  int idx = blockIdx.x * 256 + threadIdx.x;
  if (idx >= NFC * KSZ * VOCS) return;
  int mode = diag[1];
  int o = idx / (KSZ * VOCS);
  int r = idx % (KSZ * VOCS);
  int k = r / VOCS, v = r % VOCS;
  float acc = 0.f;
  for (int i = 0; i < EMBD; ++i)
    acc += ldany(emb, (size_t)v * EMBD + i, mode) * ldany(cW, ((size_t)o * EMBD + i) * KSZ + k, mode);
  Mtab[idx] = acc;
}

// ---------- a_s = x @ Ws, a_d = x @ Wd
__global__ __launch_bounds__(256) void k_asd(const void* x, const float* Ws, const float* Wd,
                                             float* a_s, float* a_d, const int* diag) {
  __shared__ unsigned short xs[256 * FD];
  __shared__ float ws_sh[FD * HEADS], wd_sh[FD * HEADS];
  int mode = diag[1];
  int nb = blockIdx.x * 256, t = threadIdx.x;
  for (int e = t; e < FD * HEADS; e += 256) { ws_sh[e] = Ws[e]; wd_sh[e] = Wd[e]; }
  for (int e = t; e < 256 * FD; e += 256) {
    int r = e / FD, c = e % FD;
    int gn = nb + r;
    float xv = (gn < NODES) ? ldany(x, (size_t)gn * FD + c, mode) : 0.f;
    bf16 tb = __float2bfloat16(xv);
    unsigned short us; __builtin_memcpy(&us, &tb, 2);
    xs[e] = us;
  }
  __syncthreads();
  int n = nb + t;
  if (n >= NODES) return;
  float as[HEADS], ad[HEADS];
#pragma unroll
  for (int hd = 0; hd < HEADS; ++hd) { as[hd] = 0.f; ad[hd] = 0.f; }
  for (int f = 0; f < FD; ++f) {
    float xv = us2f(xs[t * FD + f]);
#pragma unroll
    for (int hd = 0; hd < HEADS; ++hd) {
      as[hd] += xv * ws_sh[f * HEADS + hd];
      ad[hd] += xv * wd_sh[f * HEADS + hd];
    }
  }
#pragma unroll
  for (int hd = 0; hd < HEADS; ++hd) {
    a_s[n * HEADS + hd] = as[hd];
    a_d[n * HEADS + hd] = ad[hd];
  }
}

// ---------- CSR build
__global__ void k_count(const int* ei, int* cnt, int* diag) {
  int e = blockIdx.x * 256 + threadIdx.x;
  if (e >= ETOT) return;
  int d = (e < EDG) ? ei[EDG + e] : (e - EDG);
  if ((unsigned)d >= NODES) { atomicOr(diag, 8192); d = 0; }
  atomicAdd(&cnt[d], 1);
}

__global__ __launch_bounds__(1024) void k_scan(const int* cnt, int* rowstart) {
  __shared__ int sh[1024];
  __shared__ int carry;
  int t = threadIdx.x;
  if (t == 0) carry = 0;
  __syncthreads();
  for (int c = 0; c < (NODES + 1023) / 1024; ++c) {
    int i = c * 1024 + t;
    int v = (i < NODES) ? cnt[i] : 0;
    sh[t] = v;
    __syncthreads();
    for (int off = 1; off < 1024; off <<= 1) {
      int add = (t >= off) ? sh[t - off] : 0;
      __syncthreads();
      sh[t] += add;
      __syncthreads();
    }
    int tot = sh[1023];
    int excl = sh[t] - v + carry;
    if (i < NODES) rowstart[i] = excl;
    __syncthreads();
    if (t == 0) carry += tot;
    __syncthreads();
  }
  if (t == 0) rowstart[NODES] = carry;
}

__global__ void k_dinv(const int* cnt, float* dinv) {
  int n = blockIdx.x * 256 + threadIdx.x;
  if (n >= NODES) return;
  int d = cnt[n];
  dinv[n] = rsqrtf((float)(d > 0 ? d : 1));
}

__global__ void k_scatter(const int* ei, const int* rowstart, int* cur, int* es_src,
                          int* diag) {
  int e = blockIdx.x * 256 + threadIdx.x;
  if (e >= ETOT) return;
  int s, d;
  if (e < EDG) { s = ei[e]; d = ei[EDG + e]; } else { s = e - EDG; d = s; }
  if ((unsigned)d >= NODES) { atomicOr(diag, 8192); d = 0; }
  if ((unsigned)s >= NODES) { atomicOr(diag, 8192); s = 0; }
  int pos = rowstart[d] + atomicAdd(&cur[d], 1);
  if ((unsigned)pos < (unsigned)ETOT) es_src[pos] = s;
  else atomicOr(diag, 1);
}

__global__ void k_csrchk(const int* cnt, const int* cur, const int* rowst, int* diag) {
  int n = blockIdx.x * 256 + threadIdx.x;
  if (n < NODES && cur[n] != cnt[n]) atomicOr(diag, 1);
  if (n == 0 && rowst[NODES] != ETOT) atomicOr(diag, 1);
}

// ---------- GAT aggregation -> x1p[MPAD][KP2]; h rows stride HP, uint2 gather
__global__ __launch_bounds__(256) void k_gat(const int* es_src, const int* rowstart,
                                             const float* a_s, const float* a_d,
                                             const bf16* h, const void* gat_b, bf16* x1,
                                             int* diag) {
  int d = blockIdx.x, t = threadIdx.x;
  __shared__ float ad_sh[HEADS], m_sh[HEADS], den_sh[HEADS];
  __shared__ float exs[256 * HEADS];
  __shared__ int ssrc[256];
  __shared__ float wred[4 * HEADS];
  int mode = diag[1];
  int start = rowstart[d], end = rowstart[d + 1];
  if (t < HEADS) ad_sh[t] = a_d[d * HEADS + t];
  __syncthreads();

  // phase A: per-head max of leaky_relu(a_s[s]+a_d[d])
  float mx[HEADS];
#pragma unroll
  for (int hd = 0; hd < HEADS; ++hd) mx[hd] = -INFINITY;
  for (int e = start + t; e < end; e += 256) {
    int s = es_src[e];
    if ((unsigned)s >= NODES) { atomicOr(diag, 1); s = 0; }
#pragma unroll
    for (int hd = 0; hd < HEADS; ++hd) {
      float v = a_s[s * HEADS + hd] + ad_sh[hd];
      v = v > 0.f ? v : 0.2f * v;
      mx[hd] = fmaxf(mx[hd], v);
    }
  }
#pragma unroll
  for (int hd = 0; hd < HEADS; ++hd)
    for (int off = 32; off; off >>= 1) mx[hd] = fmaxf(mx[hd], __shfl_down(mx[hd], off, 64));
  int w = t >> 6, lane = t & 63;
  if (lane == 0) {
#pragma unroll
    for (int hd = 0; hd < HEADS; ++hd) wred[w * HEADS + hd] = mx[hd];
  }
  __syncthreads();
  if (t < HEADS)
    m_sh[t] = fmaxf(fmaxf(wred[t], wred[HEADS + t]), fmaxf(wred[2 * HEADS + t], wred[3 * HEADS + t]));
  __syncthreads();

  // phase B: exp + den + vectorized gather (thread t<196 owns feats 4t..4t+3)
  float acc[4] = {0.f, 0.f, 0.f, 0.f};
  float den[HEADS];
#pragma unroll
  for (int hd = 0; hd < HEADS; ++hd) den[hd] = 0.f;
  int fb = t * 4;
  int hh[4];
#pragma unroll
  for (int k = 0; k < 4; ++k) {
    int f = fb + k;
    hh[k] = (f < HIDD) ? (f / FD) : (HEADS - 1);
  }
  for (int base = start; base < end; base += 256) {
    int ce = base + t;
    if (ce < end) {
      int s = es_src[ce];
      if ((unsigned)s >= NODES) { atomicOr(diag, 1); s = 0; }
      ssrc[t] = s;
#pragma unroll
      for (int hd = 0; hd < HEADS; ++hd) {
        float v = a_s[s * HEADS + hd] + ad_sh[hd];
        v = v > 0.f ? v : 0.2f * v;
        float ex = expf(v - m_sh[hd]);
        exs[t * HEADS + hd] = ex;
        den[hd] += ex;
      }
    }
    __syncthreads();
    int cnt2 = end - base; if (cnt2 > 256) cnt2 = 256;
    if (t < 196) {
      for (int ce2 = 0; ce2 < cnt2; ++ce2) {
        int ss = ssrc[ce2];
        uint2 u = *(const uint2*)(h + (size_t)ss * HP + fb);
        acc[0] += exs[ce2 * HEADS + hh[0]] * us2f((unsigned short)(u.x & 0xffffu));
        acc[1] += exs[ce2 * HEADS + hh[1]] * us2f((unsigned short)(u.x >> 16));
        acc[2] += exs[ce2 * HEADS + hh[2]] * us2f((unsigned short)(u.y & 0xffffu));
        acc[3] += exs[ce2 * HEADS + hh[3]] * us2f((unsigned short)(u.y >> 16));
      }
    }
    __syncthreads();
  }
#pragma unroll
  for (int hd = 0; hd < HEADS; ++hd)
    for (int off = 32; off; off >>= 1) den[hd] += __shfl_down(den[hd], off, 64);
  if (lane == 0) {
#pragma unroll
    for (int hd = 0; hd < HEADS; ++hd) wred[w * HEADS + hd] = den[hd];
  }
  __syncthreads();
  if (t < HEADS)
    den_sh[t] = wred[t] + wred[HEADS + t] + wred[2 * HEADS + t] + wred[3 * HEADS + t];
  __syncthreads();

  if (t < 196) {
    bool dn = nanf_(den_sh[hh[0]]) || nanf_(den_sh[hh[3]]);
    bool an = nanf_(acc[0]) || nanf_(acc[3]);
    if (dn) atomicOr(diag, 2);
    else if (an) atomicOr(diag, 8);
  }
  // store: feats < HIDD get value; pad cols [HIDD, KP2) get exact zero
  if (t < 200) {  // fb up to 796..799 covers all KP2=800 cols
    size_t rb = (size_t)d * KP2;
#pragma unroll
    for (int k = 0; k < 4; ++k) {
      int f = fb + k;
      float o = 0.f;
      if (f < HIDD)
        o = fmaxf(acc[k] / den_sh[hh[k]] + ldany(gat_b, f, mode), 0.f);
      x1[rb + f] = __float2bfloat16(o);
    }
  }
}

// ---------- GCN aggregation + bias + relu + pool; h2 stride HP, uint2 gather
__global__ __launch_bounds__(256) void k_gcn(const int* es_src, const int* rowstart,
                                             const float* dinv, const bf16* h2,
                                             const void* gcn_b, const int* batch,
                                             float* xg_pool, int* diag) {
  int d = blockIdx.x, t = threadIdx.x;
  __shared__ float nrm[256];
  __shared__ int ssrc[256];
  int mode = diag[1];
  int start = rowstart[d], end = rowstart[d + 1];
  float dd = dinv[d];
  int b = batch[d];
  if ((unsigned)b >= GB) { atomicOr(diag, 8192); b = 0; }
  float acc[4] = {0.f, 0.f, 0.f, 0.f};
  int fb = t * 4;
  for (int base = start; base < end; base += 256) {
    int ce = base + t;
    if (ce < end) {
      int s = es_src[ce];
      if ((unsigned)s >= NODES) { atomicOr(diag, 1); s = 0; }
      ssrc[t] = s;
      nrm[t] = dinv[s] * dd;
    }
    __syncthreads();
    int cnt2 = end - base; if (cnt2 > 256) cnt2 = 256;
    if (t < 196) {
      for (int ce2 = 0; ce2 < cnt2; ++ce2) {
        int ss = ssrc[ce2];
        float nv = nrm[ce2];
        uint2 u = *(const uint2*)(h2 + (size_t)ss * HP + fb);
        acc[0] += nv * us2f((unsigned short)(u.x & 0xffffu));
        acc[1] += nv * us2f((unsigned short)(u.x >> 16));
        acc[2] += nv * us2f((unsigned short)(u.y & 0xffffu));
        acc[3] += nv * us2f((unsigned short)(u.y >> 16));
      }
    }
    __syncthreads();
  }
  if (t < 196) {
    if (nanf_(acc[0]) || nanf_(acc[3])) atomicOr(diag, 16);
#pragma unroll
    for (int k = 0; k < 4; ++k) {
      int f = fb + k;
      if (f < HIDD) {
        float v = fmaxf(acc[k] + ldany(gcn_b, f, mode), 0.f);
        atomicAdd(&xg_pool[b * HIDD + f], v);
      }
    }
  }
}

// ---------- conv via LUT -> bf16 output
__global__ __launch_bounds__(256) void k_conv(const int* target, const float* Mtab,
                                              const void* cb, bf16* c, int* diag) {
  int b = blockIdx.y, tc = blockIdx.x, t = threadIdx.x;
  __shared__ float Mt[NFC * KSZ * VOCS];
  __shared__ int tg[256 + KSZ - 1];
  int mode = diag[1];
  for (int e = t; e < NFC * KSZ * VOCS; e += 256) Mt[e] = Mtab[e];
  int tbase = tc * 256;
  for (int e = t; e < 256 + KSZ - 1; e += 256) {
    int p = tbase + e;
    int tv = (p < SEQL) ? target[b * SEQL + p] : 0;
    if ((unsigned)tv >= VOCS) { atomicOr(diag, 8192); tv = 0; }
    tg[e] = tv;
  }
  __syncthreads();
  int tt = tbase + t;
  if (tt >= COUT) return;
  float acc[NFC];
#pragma unroll
  for (int o = 0; o < NFC; ++o) acc[o] = 0.f;
#pragma unroll
  for (int k = 0; k < KSZ; ++k) {
    int v = tg[t + k];
    const float* Mk = &Mt[k * VOCS + v];
#pragma unroll
    for (int o = 0; o < NFC; ++o) acc[o] += Mk[o * KSZ * VOCS];
  }
  if (nanf_(acc[0])) atomicOr(diag, 4096);
#pragma unroll
  for (int o = 0; o < NFC; ++o)
    c[(size_t)b * KFXT + o * COUT + tt] = __float2bfloat16(acc[o] + ldany(cb, o, mode));
}

// ---------- final 128->1 + diag encoding (applies relu to xf4 pre-activations)
__global__ __launch_bounds__(64) void k_out(const float* xf4, const void* o_W,
                                            const void* o_b, void* outp, const int* diag) {
  int b = blockIdx.x, lane = threadIdx.x;
  int mode = diag[1];
  float a0 = fmaxf(xf4[b * 128 + lane], 0.f);
  float a1 = fmaxf(xf4[b * 128 + 64 + lane], 0.f);
  float v = a0 * ldany(o_W, lane, mode) + a1 * ldany(o_W, 64 + lane, mode);
  for (int off = 32; off; off >>= 1) v += __shfl_down(v, off, 64);
  if (lane == 0) {
    float r = v + ldany(o_b, 0, mode);
    int dg = diag[0];
    if (dg) r = 256.f * (1 + mode) + 8.f * (float)(__ffs(dg) - 1);
    else if (nanf_(r)) r = 200.f + 100.f * mode;
    if (mode) ((float*)outp)[b] = r;
    else ((bf16*)outp)[b] = __float2bfloat16(r);
  }
}

extern "C" void kernel_launch(void* const* d_in, const int* in_sizes, int n_in,
                              void* d_out, int out_size, void* d_ws, size_t ws_size,
                              hipStream_t stream) {
  const void* x       = d_in[0];
  const int*  ei      = (const int*)d_in[1];
  const int*  batch   = (const int*)d_in[2];
  const int*  target  = (const int*)d_in[3];
  const void* gat_W   = d_in[4];
  const void* a_src   = d_in[5];
  const void* a_dst   = d_in[6];
  const void* gat_b   = d_in[7];
  const void* gcn_W   = d_in[8];
  const void* gcn_b   = d_in[9];
  const void* fcg1_W  = d_in[10];
  const void* fcg1_b  = d_in[11];
  const void* fcg2_W  = d_in[12];
  const void* fcg2_b  = d_in[13];
  const void* emb     = d_in[14];
  const void* cW      = d_in[15];
  const void* cb      = d_in[16];
  const void* fxt_W   = d_in[17];
  const void* fxt_b   = d_in[18];
  const void* f1_W    = d_in[19];
  const void* f1_b    = d_in[20];
  const void* f2_W    = d_in[21];
  const void* f2_b    = d_in[22];
  const void* f3_W    = d_in[23];
  const void* f3_b    = d_in[24];
  const void* f4_W    = d_in[25];
  const void* f4_b    = d_in[26];
  const void* o_W     = d_in[27];
  const void* o_b     = d_in[28];

  char* w = (char*)d_ws;
  size_t off = 0;
  auto alloc = [&](size_t bytes) -> void* {
    void* p = w + off;
    off = (off + bytes + 255) & ~(size_t)255;
    return p;
  };
  bf16*  h_buf   = (bf16*)alloc((size_t)NODES * HP * 2);    // h, then h2 (stride HP)
  bf16*  x1p     = (bf16*)alloc((size_t)MPAD * KP2 * 2);    // x1 padded [MPAD][800]
  bf16*  xpad    = (bf16*)alloc((size_t)MPAD * KP1 * 2);    // x padded  [MPAD][96]
  bf16*  gatWt   = (bf16*)alloc((size_t)NPADB * KP1 * 2);
  bf16*  gcnWt   = (bf16*)alloc((size_t)NPADB * KP2 * 2);
  float* a_s     = (float*)alloc((size_t)NODES * HEADS * 4);
  float* a_d     = (float*)alloc((size_t)NODES * HEADS * 4);
  float* Ws      = (float*)alloc(FD * HEADS * 4);
  float* Wd      = (float*)alloc(FD * HEADS * 4);
  float* Mtab    = (float*)alloc(NFC * KSZ * VOCS * 4);
  int*   rowst   = (int*)alloc((NODES + 1) * 4);
  float* dinv    = (float*)alloc(NODES * 4);
  bf16*  c_buf   = (bf16*)alloc((size_t)GB * KFXT * 2);     // bf16 conv output
  // ---- contiguous zero-initialized region (single memset) ----
  size_t zoff = off;
  int*   cnt     = (int*)alloc(NODES * 4);
  int*   cur     = (int*)alloc(NODES * 4);
  int*   es_src  = (int*)alloc((size_t)ETOT * 4);
  float* xg_pool = (float*)alloc((size_t)GB * HIDD * 4);
  float* xg1     = (float*)alloc((size_t)GB * 1500 * 4);
  float* xc      = (float*)alloc((size_t)GB * 256 * 4);
  float* xf1     = (float*)alloc((size_t)GB * 1024 * 4);
  float* xf2     = (float*)alloc((size_t)GB * 512 * 4);
  float* xf3     = (float*)alloc((size_t)GB * 256 * 4);
  float* xf4     = (float*)alloc((size_t)GB * 128 * 4);
  int*   diag    = (int*)alloc(2 * 4);
  size_t zlen = off - zoff;

  hipMemsetAsync(w + zoff, 0, zlen, stream);

  k_detect<<<1, 256, 0, stream>>>(x, diag);

  // input prep (mode-aware) -> padded bf16 operands for MFMA
  k_pad_x<<<(MPAD * KP1 + 255) / 256, 256, 0, stream>>>(x, xpad, diag);
  k_tr_gatw<<<(NPADB * KP1 + 255) / 256, 256, 0, stream>>>(gat_W, gatWt, diag);
  k_tr_gcnw<<<(NPADB * KP2 + 255) / 256, 256, 0, stream>>>(gcn_W, gcnWt, diag);
  k_zero_x1pad<<<((MPAD - NODES) * KP2 + 255) / 256, 256, 0, stream>>>(x1p);

  k_prep_ws<<<(FD * HEADS + 255) / 256, 256, 0, stream>>>(gat_W, a_src, a_dst, Ws, Wd, diag);
  k_prep_mtab<<<(NFC * KSZ * VOCS + 255) / 256, 256, 0, stream>>>(emb, cW, Mtab, diag);

  // h = x @ gat_W   (MFMA, row stride HP)
  k_gemm_mfma<<<dim3(NPADB / NT, MPAD / MT), 256, 0, stream>>>(
      xpad, KP1, gatWt, KP1, h_buf, HP, HP, NODES, KP1);
  k_asd<<<(NODES + 255) / 256, 256, 0, stream>>>(x, Ws, Wd, a_s, a_d, diag);

  // CSR
  k_count<<<(ETOT + 255) / 256, 256, 0, stream>>>(ei, cnt, diag);
  k_scan<<<1, 1024, 0, stream>>>(cnt, rowst);
  k_dinv<<<(NODES + 255) / 256, 256, 0, stream>>>(cnt, dinv);
  k_scatter<<<(ETOT + 255) / 256, 256, 0, stream>>>(ei, rowst, cur, es_src, diag);
  k_csrchk<<<(NODES + 255) / 256, 256, 0, stream>>>(cnt, cur, rowst, diag);

  k_gat<<<NODES, 256, 0, stream>>>(es_src, rowst, a_s, a_d, h_buf, gat_b, x1p, diag);

  // h2 = x1 @ gcn_W  (MFMA; h_buf reused, stride HP)
  k_gemm_mfma<<<dim3(NPADB / NT, MPAD / MT), 256, 0, stream>>>(
      x1p, KP2, gcnWt, KP2, h_buf, HP, HP, NODES, KP2);

  k_gcn<<<NODES, 256, 0, stream>>>(es_src, rowst, dinv, h_buf, gcn_b, batch, xg_pool, diag);

  k_conv<<<dim3(4, GB), 256, 0, stream>>>(target, Mtab, cb, c_buf, diag);

  // MLP chain via MFMA; pre-activation outputs, relu applied on consumer A-load
  k_mlp_mfma<<<dim3(24, 4), 256, 0, stream>>>(xg_pool, HIDD, fcg1_W, fcg1_b,
                                              xg1, 1500, 0, GB, 1500, HIDD, 4, 0, 0, diag);
  k_mlp_mfma<<<dim3(2, 16), 256, 0, stream>>>(xg1, 1500, fcg2_W, fcg2_b,
                                              xc, 256, 0, GB, 128, 1500, 16, 1, 0, diag);
  k_mlp_mfma<<<dim3(2, 64), 256, 0, stream>>>(c_buf, KFXT, fxt_W, fxt_b,
                                              xc, 256, 128, GB, 128, KFXT, 64, 0, 1, diag);
  k_mlp_mfma<<<dim3(16, 4), 256, 0, stream>>>(xc, 256, f1_W, f1_b,
                                              xf1, 1024, 0, GB, 1024, 256, 4, 0, 0, diag);
  k_mlp_mfma<<<dim3(8, 8), 256, 0, stream>>>(xf1, 1024, f2_W, f2_b,
                                             xf2, 512, 0, GB, 512, 1024, 8, 1, 0, diag);
  k_mlp_mfma<<<dim3(4, 8), 256, 0, stream>>>(xf2, 512, f3_W, f3_b,
                                             xf3, 256, 0, GB, 256, 512, 8, 1, 0, diag);
  k_mlp_mfma<<<dim3(2, 8), 256, 0, stream>>>(xf3, 256, f4_W, f4_b,
                                             xf4, 128, 0, GB, 128, 256, 8, 1, 0, diag);
  k_out<<<GB, 64, 0, stream>>>(xf4, o_W, o_b, d_out, diag);
}

// Round 8
// 999.599 us; speedup vs baseline: 1.1142x; 1.1142x over previous
//
#include <hip/hip_runtime.h>
#include <hip/hip_bf16.h>
#include <math.h>

typedef __hip_bfloat16 bf16;
typedef __attribute__((ext_vector_type(8))) short short8v;   // 8 bf16 (4 VGPRs)
typedef __attribute__((ext_vector_type(4))) float float4v;   // mfma acc

#define NODES 20000
#define EDG   400000
#define ETOT  (EDG + NODES)
#define GB    200
#define HEADS 10
#define FD    78
#define HIDD  780
#define SEQL  1000
#define VOCS  26
#define EMBD  128
#define NFC   32
#define KSZ   8
#define COUT  993
#define KFXT  (NFC * COUT)

#define MPAD  20096   // 157*128
#define NPADB 896     // 7*128
#define KP1   96      // K=78 padded to 3*32
#define KP2   800     // K=780 padded to 25*32
#define HP    784     // padded h/h2/x2 row stride (196*4) for uint2 gathers

// diag[0] bits: 1=CSR structural, 2=gat logits NaN, 8=gat acc NaN, 16=gcn acc NaN,
// 4096=conv NaN, 8192=idx OOB
// diag[1]: 0 = inputs are bf16, 1 = inputs are fp32

__device__ __forceinline__ float us2f(unsigned short u) {
  unsigned int i = ((unsigned int)u) << 16; float f; __builtin_memcpy(&f, &i, 4); return f;
}
__device__ __forceinline__ float b2f(bf16 v) { return __bfloat162float(v); }
__device__ __forceinline__ float ldany(const void* p, size_t i, int m) {
  if (m) return ((const float*)p)[i];
  return b2f(((const bf16*)p)[i]);
}
__device__ __forceinline__ bool nanf_(float v) { return v != v; }
__device__ __forceinline__ unsigned short f2us(float v) {
  bf16 b = __float2bfloat16(v); unsigned short u; __builtin_memcpy(&u, &b, 2); return u;
}

// ---------- runtime dtype detection on x
__global__ void k_detect(const void* x, int* diag) {
  int t = threadIdx.x;
  const unsigned short* u = (const unsigned short*)x;
  int hit = 0;
  for (int i = t; i < 4096; i += 256) {
    float v = us2f(u[i]);
    if (nanf_(v) || fabsf(v) > 1e6f) hit = 1;
  }
  if (hit) diag[1] = 1;  // benign race: all writers store 1
}

// ---------- pad/convert x -> xpad[MPAD][KP1] bf16 (zeros in pads)
__global__ void k_pad_x(const void* x, bf16* xpad, const int* diag) {
  int idx = blockIdx.x * 256 + threadIdx.x;
  if (idx >= MPAD * KP1) return;
  int mode = diag[1];
  int m = idx / KP1, k = idx % KP1;
  float v = (m < NODES && k < FD) ? ldany(x, (size_t)m * FD + k, mode) : 0.f;
  xpad[idx] = __float2bfloat16(v);
}

// ---------- transpose gat_W [78][780] -> gatWt[NPADB][KP1]
__global__ void k_tr_gatw(const void* gw, bf16* Wt, const int* diag) {
  int idx = blockIdx.x * 256 + threadIdx.x;
  if (idx >= NPADB * KP1) return;
  int mode = diag[1];
  int n = idx / KP1, k = idx % KP1;
  float v = (n < HIDD && k < FD) ? ldany(gw, (size_t)k * HIDD + n, mode) : 0.f;
  Wt[idx] = __float2bfloat16(v);
}

// ---------- transpose gcn_W [780][780] -> gcnWt[NPADB][KP2]
__global__ void k_tr_gcnw(const void* gw, bf16* Wt, const int* diag) {
  int idx = blockIdx.x * 256 + threadIdx.x;
  if (idx >= NPADB * KP2) return;
  int mode = diag[1];
  int n = idx / KP2, k = idx % KP2;
  float v = (n < HIDD && k < HIDD) ? ldany(gw, (size_t)k * HIDD + n, mode) : 0.f;
  Wt[idx] = __float2bfloat16(v);
}

// ---------- zero pad rows of x1p (rows 20000..20095)
__global__ void k_zero_x1pad(bf16* x1p) {
  int i = blockIdx.x * 256 + threadIdx.x;
  if (i < (MPAD - NODES) * KP2)
    x1p[(size_t)NODES * KP2 + i] = __float2bfloat16(0.f);
}

// ---------- MFMA bf16 GEMM: C[gm*ldc+gn] = A[M x Kp (lda)] @ Bt[n][k] (ldb)
#define MT 128
#define NT 128
#define BK 32
#define LP 40   // LDS row stride (bf16): 80B rows -> 16B-aligned b128
__global__ __launch_bounds__(256) void k_gemm_mfma(const bf16* A, int lda,
                                                   const bf16* Bt, int ldb,
                                                   bf16* C, int ldc, int Ncap,
                                                   int M, int Kp) {
  __shared__ __align__(16) bf16 As[MT * LP];
  __shared__ __align__(16) bf16 Bs[NT * LP];
  int t = threadIdx.x;
  int lane = t & 63, w = t >> 6;
  int wr = (w >> 1) * 64, wc = (w & 1) * 64;
  int quad = lane >> 4, mr = lane & 15;
  int m0 = blockIdx.y * MT, n0 = blockIdx.x * NT;
  float4v acc[4][4];
#pragma unroll
  for (int i = 0; i < 4; ++i)
#pragma unroll
    for (int j = 0; j < 4; ++j) acc[i][j] = (float4v){0.f, 0.f, 0.f, 0.f};

  for (int kc = 0; kc < Kp; kc += BK) {
#pragma unroll
    for (int i = 0; i < 4; ++i) {
      int c = t + i * 256;
      int row = c >> 3, col = (c & 7) * 4;
      *(uint2*)&As[row * LP + col] =
          *(const uint2*)&A[(size_t)(m0 + row) * lda + kc + col];
      *(uint2*)&Bs[row * LP + col] =
          *(const uint2*)&Bt[(size_t)(n0 + row) * ldb + kc + col];
    }
    __syncthreads();
    short8v af[4], bfr[4];
#pragma unroll
    for (int i = 0; i < 4; ++i)
      af[i] = *(const short8v*)&As[(wr + i * 16 + mr) * LP + quad * 8];
#pragma unroll
    for (int j = 0; j < 4; ++j)
      bfr[j] = *(const short8v*)&Bs[(wc + j * 16 + mr) * LP + quad * 8];
#pragma unroll
    for (int i = 0; i < 4; ++i)
#pragma unroll
      for (int j = 0; j < 4; ++j)
        acc[i][j] = __builtin_amdgcn_mfma_f32_16x16x32_bf16(af[i], bfr[j], acc[i][j], 0, 0, 0);
    __syncthreads();
  }
#pragma unroll
  for (int i = 0; i < 4; ++i) {
    int gm0 = m0 + wr + i * 16 + quad * 4;
#pragma unroll
    for (int j = 0; j < 4; ++j) {
      int gn = n0 + wc + j * 16 + mr;
      if (gn >= Ncap) continue;
#pragma unroll
      for (int r = 0; r < 4; ++r) {
        int gm = gm0 + r;
        if (gm < M) C[(size_t)gm * ldc + gn] = __float2bfloat16(acc[i][j][r]);
      }
    }
  }
}

// ---------- MFMA small-M dense layer: out[M,N] (+)= A[M,K] @ B[K,N]
#define MLP_NT 64
#define MLP_BK 32
#define MLP_MT 208
#define MLP_LP 40
__global__ __launch_bounds__(256) void k_mlp_mfma(const void* A, int lda, const void* Bw,
                                                  const void* bias, float* out, int ostride,
                                                  int ooff, int M, int Nn, int K,
                                                  int ksplit, int aRelu, int aBf16,
                                                  const int* diag) {
  __shared__ __align__(16) bf16 As[MLP_MT * MLP_LP];
  __shared__ __align__(16) bf16 Bs[MLP_NT * MLP_LP];
  int mode = diag[1];
  int t = threadIdx.x;
  int lane = t & 63, w = t >> 6;
  int quad = lane >> 4, mr = lane & 15;
  int n0 = blockIdx.x * MLP_NT;
  int kz = blockIdx.y;
  int nchunks = (K + MLP_BK - 1) / MLP_BK;
  int cpk = (nchunks + ksplit - 1) / ksplit;
  int c0 = kz * cpk, c1 = c0 + cpk;
  if (c1 > nchunks) c1 = nchunks;
  float4v acc[13];
#pragma unroll
  for (int i = 0; i < 13; ++i) acc[i] = (float4v){0.f, 0.f, 0.f, 0.f};

  for (int c = c0; c < c1; ++c) {
    int k0 = c * MLP_BK;
    if (aBf16) {
      const bf16* Ab = (const bf16*)A;
      for (int e = t; e < MLP_MT * 4; e += 256) {
        int row = e >> 2, c8 = (e & 3) * 8;
        int gk = k0 + c8;
        if (row < M && gk + 7 < K) {
          *(uint4*)&As[row * MLP_LP + c8] = *(const uint4*)&Ab[(size_t)row * lda + gk];
        } else {
#pragma unroll
          for (int kk = 0; kk < 8; ++kk) {
            float v = (row < M && gk + kk < K) ? b2f(Ab[(size_t)row * lda + gk + kk]) : 0.f;
            As[row * MLP_LP + c8 + kk] = __float2bfloat16(v);
          }
        }
      }
    } else {
      const float* Af = (const float*)A;
      for (int e = t; e < MLP_MT * 8; e += 256) {
        int row = e >> 3, c4 = (e & 7) * 4;
        int gk = k0 + c4;
        float4 v4 = {0.f, 0.f, 0.f, 0.f};
        if (row < M) {
          if (gk + 3 < K) {
            v4 = *(const float4*)&Af[(size_t)row * lda + gk];
          } else {
            v4.x = (gk + 0 < K) ? Af[(size_t)row * lda + gk + 0] : 0.f;
            v4.y = (gk + 1 < K) ? Af[(size_t)row * lda + gk + 1] : 0.f;
            v4.z = (gk + 2 < K) ? Af[(size_t)row * lda + gk + 2] : 0.f;
            v4.w = (gk + 3 < K) ? Af[(size_t)row * lda + gk + 3] : 0.f;
          }
        }
        if (aRelu) {
          v4.x = fmaxf(v4.x, 0.f); v4.y = fmaxf(v4.y, 0.f);
          v4.z = fmaxf(v4.z, 0.f); v4.w = fmaxf(v4.w, 0.f);
        }
        bf16* dst = &As[row * MLP_LP + c4];
        dst[0] = __float2bfloat16(v4.x); dst[1] = __float2bfloat16(v4.y);
        dst[2] = __float2bfloat16(v4.z); dst[3] = __float2bfloat16(v4.w);
      }
    }
    for (int e = t; e < MLP_NT * MLP_BK; e += 256) {
      int k = e >> 6, col = e & 63;
      int gk = k0 + k, gn = n0 + col;
      float v = (gn < Nn && gk < K) ? ldany(Bw, (size_t)gk * Nn + gn, mode) : 0.f;
      Bs[col * MLP_LP + k] = __float2bfloat16(v);
    }
    __syncthreads();
    short8v bf = *(const short8v*)&Bs[(w * 16 + mr) * MLP_LP + quad * 8];
#pragma unroll
    for (int i = 0; i < 13; ++i) {
      short8v af = *(const short8v*)&As[(i * 16 + mr) * MLP_LP + quad * 8];
      acc[i] = __builtin_amdgcn_mfma_f32_16x16x32_bf16(af, bf, acc[i], 0, 0, 0);
    }
    __syncthreads();
  }
  int gn = n0 + w * 16 + mr;
  if (gn >= Nn) return;
  float bs = (kz == 0) ? ldany(bias, gn, mode) : 0.f;
#pragma unroll
  for (int i = 0; i < 13; ++i) {
    int gm0 = i * 16 + quad * 4;
#pragma unroll
    for (int r = 0; r < 4; ++r) {
      int gm = gm0 + r;
      if (gm >= M) break;
      float v = acc[i][r] + bs;
      float* op = &out[(size_t)gm * ostride + ooff + gn];
      if (ksplit == 1) *op = v;
      else atomicAdd(op, v);
    }
  }
}

// ---------- fold gat_a: Ws[k][hd] = sum_f W[k,hd*F+f]*a_src[hd,f]
__global__ void k_prep_ws(const void* gat_W, const void* a_src, const void* a_dst,
                          float* Ws, float* Wd, const int* diag) {
  int idx = blockIdx.x * 256 + threadIdx.x;
  if (idx >= FD * HEADS) return;
  int mode = diag[1];
  int k = idx / HEADS, hd = idx % HEADS;
  float s = 0.f, d = 0.f;
  for (int f = 0; f < FD; ++f) {
    float w = ldany(gat_W, (size_t)k * HIDD + hd * FD + f, mode);
    s += w * ldany(a_src, (size_t)hd * FD + f, mode);
    d += w * ldany(a_dst, (size_t)hd * FD + f, mode);
  }
  Ws[k * HEADS + hd] = s;
  Wd[k * HEADS + hd] = d;
}

// ---------- conv LUT: Mtab[(o*KSZ+k)*VOCS+v] = sum_i emb[v,i]*cW[o,i,k]
__global__ void k_prep_mtab(const void* emb, const void* cW, float* Mtab, const int* diag) {
  int idx = blockIdx.x * 256 + threadIdx.x;
  if (idx >= NFC * KSZ * VOCS) return;
  int mode = diag[1];
  int o = idx / (KSZ * VOCS);
  int r = idx % (KSZ * VOCS);
  int k = r / VOCS, v = r % VOCS;
  float acc = 0.f;
  for (int i = 0; i < EMBD; ++i)
    acc += ldany(emb, (size_t)v * EMBD + i, mode) * ldany(cW, ((size_t)o * EMBD + i) * KSZ + k, mode);
  Mtab[idx] = acc;
}

// ---------- a_s = x @ Ws, a_d = x @ Wd
__global__ __launch_bounds__(256) void k_asd(const void* x, const float* Ws, const float* Wd,
                                             float* a_s, float* a_d, const int* diag) {
  __shared__ unsigned short xs[256 * FD];
  __shared__ float ws_sh[FD * HEADS], wd_sh[FD * HEADS];
  int mode = diag[1];
  int nb = blockIdx.x * 256, t = threadIdx.x;
  for (int e = t; e < FD * HEADS; e += 256) { ws_sh[e] = Ws[e]; wd_sh[e] = Wd[e]; }
  for (int e = t; e < 256 * FD; e += 256) {
    int r = e / FD, c = e % FD;
    int gn = nb + r;
    float xv = (gn < NODES) ? ldany(x, (size_t)gn * FD + c, mode) : 0.f;
    xs[e] = f2us(xv);
  }
  __syncthreads();
  int n = nb + t;
  if (n >= NODES) return;
  float as[HEADS], ad[HEADS];
#pragma unroll
  for (int hd = 0; hd < HEADS; ++hd) { as[hd] = 0.f; ad[hd] = 0.f; }
  for (int f = 0; f < FD; ++f) {
    float xv = us2f(xs[t * FD + f]);
#pragma unroll
    for (int hd = 0; hd < HEADS; ++hd) {
      as[hd] += xv * ws_sh[f * HEADS + hd];
      ad[hd] += xv * wd_sh[f * HEADS + hd];
    }
  }
#pragma unroll
  for (int hd = 0; hd < HEADS; ++hd) {
    a_s[n * HEADS + hd] = as[hd];
    a_d[n * HEADS + hd] = ad[hd];
  }
}

// ---------- CSR build
__global__ void k_count(const int* ei, int* cnt, int* diag) {
  int e = blockIdx.x * 256 + threadIdx.x;
  if (e >= ETOT) return;
  int d = (e < EDG) ? ei[EDG + e] : (e - EDG);
  if ((unsigned)d >= NODES) { atomicOr(diag, 8192); d = 0; }
  atomicAdd(&cnt[d], 1);
}

__global__ __launch_bounds__(1024) void k_scan(const int* cnt, int* rowstart) {
  __shared__ int sh[1024];
  __shared__ int carry;
  int t = threadIdx.x;
  if (t == 0) carry = 0;
  __syncthreads();
  for (int c = 0; c < (NODES + 1023) / 1024; ++c) {
    int i = c * 1024 + t;
    int v = (i < NODES) ? cnt[i] : 0;
    sh[t] = v;
    __syncthreads();
    for (int off = 1; off < 1024; off <<= 1) {
      int add = (t >= off) ? sh[t - off] : 0;
      __syncthreads();
      sh[t] += add;
      __syncthreads();
    }
    int tot = sh[1023];
    int excl = sh[t] - v + carry;
    if (i < NODES) rowstart[i] = excl;
    __syncthreads();
    if (t == 0) carry += tot;
    __syncthreads();
  }
  if (t == 0) rowstart[NODES] = carry;
}

__global__ void k_dinv(const int* cnt, float* dinv) {
  int n = blockIdx.x * 256 + threadIdx.x;
  if (n >= NODES) return;
  int d = cnt[n];
  dinv[n] = rsqrtf((float)(d > 0 ? d : 1));
}

__global__ void k_scatter(const int* ei, const int* rowstart, int* cur, int* es_src,
                          int* diag) {
  int e = blockIdx.x * 256 + threadIdx.x;
  if (e >= ETOT) return;
  int s, d;
  if (e < EDG) { s = ei[e]; d = ei[EDG + e]; } else { s = e - EDG; d = s; }
  if ((unsigned)d >= NODES) { atomicOr(diag, 8192); d = 0; }
  if ((unsigned)s >= NODES) { atomicOr(diag, 8192); s = 0; }
  int pos = rowstart[d] + atomicAdd(&cur[d], 1);
  if ((unsigned)pos < (unsigned)ETOT) es_src[pos] = s;
  else atomicOr(diag, 1);
}

__global__ void k_csrchk(const int* cnt, const int* cur, const int* rowst, int* diag) {
  int n = blockIdx.x * 256 + threadIdx.x;
  if (n < NODES && cur[n] != cnt[n]) atomicOr(diag, 1);
  if (n == 0 && rowst[NODES] != ETOT) atomicOr(diag, 1);
}

// ---------- batch segment starts (batch sorted; handles empty batches)
__global__ void k_bseg(const int* batch, int* bstart, int* diag) {
  int i = blockIdx.x * 256 + threadIdx.x;
  if (i >= NODES) return;
  int bi = batch[i];
  if ((unsigned)bi >= GB) { atomicOr(diag, 8192); bi = GB - 1; }
  int bp;
  if (i == 0) bp = -1;
  else {
    bp = batch[i - 1];
    if ((unsigned)bp >= GB) bp = GB - 1;
  }
  for (int b = bp + 1; b <= bi; ++b) bstart[b] = i;
  if (i == NODES - 1)
    for (int b = bi + 1; b <= GB; ++b) bstart[b] = NODES;
}

// ---------- GAT aggregation -> x1p[MPAD][KP2]; h rows stride HP, uint2 gather
__global__ __launch_bounds__(256) void k_gat(const int* es_src, const int* rowstart,
                                             const float* a_s, const float* a_d,
                                             const bf16* h, const void* gat_b, bf16* x1,
                                             int* diag) {
  int d = blockIdx.x, t = threadIdx.x;
  __shared__ float ad_sh[HEADS], m_sh[HEADS], den_sh[HEADS];
  __shared__ float exs[256 * HEADS];
  __shared__ int ssrc[256];
  __shared__ float wred[4 * HEADS];
  int mode = diag[1];
  int start = rowstart[d], end = rowstart[d + 1];
  if (t < HEADS) ad_sh[t] = a_d[d * HEADS + t];
  __syncthreads();

  float mx[HEADS];
#pragma unroll
  for (int hd = 0; hd < HEADS; ++hd) mx[hd] = -INFINITY;
  for (int e = start + t; e < end; e += 256) {
    int s = es_src[e];
    if ((unsigned)s >= NODES) { atomicOr(diag, 1); s = 0; }
#pragma unroll
    for (int hd = 0; hd < HEADS; ++hd) {
      float v = a_s[s * HEADS + hd] + ad_sh[hd];
      v = v > 0.f ? v : 0.2f * v;
      mx[hd] = fmaxf(mx[hd], v);
    }
  }
#pragma unroll
  for (int hd = 0; hd < HEADS; ++hd)
    for (int off = 32; off; off >>= 1) mx[hd] = fmaxf(mx[hd], __shfl_down(mx[hd], off, 64));
  int w = t >> 6, lane = t & 63;
  if (lane == 0) {
#pragma unroll
    for (int hd = 0; hd < HEADS; ++hd) wred[w * HEADS + hd] = mx[hd];
  }
  __syncthreads();
  if (t < HEADS)
    m_sh[t] = fmaxf(fmaxf(wred[t], wred[HEADS + t]), fmaxf(wred[2 * HEADS + t], wred[3 * HEADS + t]));
  __syncthreads();

  float acc[4] = {0.f, 0.f, 0.f, 0.f};
  float den[HEADS];
#pragma unroll
  for (int hd = 0; hd < HEADS; ++hd) den[hd] = 0.f;
  int fb = t * 4;
  int hh[4];
#pragma unroll
  for (int k = 0; k < 4; ++k) {
    int f = fb + k;
    hh[k] = (f < HIDD) ? (f / FD) : (HEADS - 1);
  }
  for (int base = start; base < end; base += 256) {
    int ce = base + t;
    if (ce < end) {
      int s = es_src[ce];
      if ((unsigned)s >= NODES) { atomicOr(diag, 1); s = 0; }
      ssrc[t] = s;
#pragma unroll
      for (int hd = 0; hd < HEADS; ++hd) {
        float v = a_s[s * HEADS + hd] + ad_sh[hd];
        v = v > 0.f ? v : 0.2f * v;
        float ex = expf(v - m_sh[hd]);
        exs[t * HEADS + hd] = ex;
        den[hd] += ex;
      }
    }
    __syncthreads();
    int cnt2 = end - base; if (cnt2 > 256) cnt2 = 256;
    if (t < 196) {
      for (int ce2 = 0; ce2 < cnt2; ++ce2) {
        int ss = ssrc[ce2];
        uint2 u = *(const uint2*)(h + (size_t)ss * HP + fb);
        acc[0] += exs[ce2 * HEADS + hh[0]] * us2f((unsigned short)(u.x & 0xffffu));
        acc[1] += exs[ce2 * HEADS + hh[1]] * us2f((unsigned short)(u.x >> 16));
        acc[2] += exs[ce2 * HEADS + hh[2]] * us2f((unsigned short)(u.y & 0xffffu));
        acc[3] += exs[ce2 * HEADS + hh[3]] * us2f((unsigned short)(u.y >> 16));
      }
    }
    __syncthreads();
  }
#pragma unroll
  for (int hd = 0; hd < HEADS; ++hd)
    for (int off = 32; off; off >>= 1) den[hd] += __shfl_down(den[hd], off, 64);
  if (lane == 0) {
#pragma unroll
    for (int hd = 0; hd < HEADS; ++hd) wred[w * HEADS + hd] = den[hd];
  }
  __syncthreads();
  if (t < HEADS)
    den_sh[t] = wred[t] + wred[HEADS + t] + wred[2 * HEADS + t] + wred[3 * HEADS + t];
  __syncthreads();

  if (t < 196) {
    bool dn = nanf_(den_sh[hh[0]]) || nanf_(den_sh[hh[3]]);
    bool an = nanf_(acc[0]) || nanf_(acc[3]);
    if (dn) atomicOr(diag, 2);
    else if (an) atomicOr(diag, 8);
  }
  if (t < 200) {  // cover all KP2=800 cols (pads get exact zero)
    size_t rb = (size_t)d * KP2;
#pragma unroll
    for (int k = 0; k < 4; ++k) {
      int f = fb + k;
      float o = 0.f;
      if (f < HIDD)
        o = fmaxf(acc[k] / den_sh[hh[k]] + ldany(gat_b, f, mode), 0.f);
      x1[rb + f] = __float2bfloat16(o);
    }
  }
}

// ---------- GCN aggregation + bias + relu -> x2b[NODES][HP] bf16 (NO atomics)
__global__ __launch_bounds__(256) void k_gcn(const int* es_src, const int* rowstart,
                                             const float* dinv, const bf16* h2,
                                             const void* gcn_b, bf16* x2b, int* diag) {
  int d = blockIdx.x, t = threadIdx.x;
  __shared__ float nrm[256];
  __shared__ int ssrc[256];
  int mode = diag[1];
  int start = rowstart[d], end = rowstart[d + 1];
  float dd = dinv[d];
  float acc[4] = {0.f, 0.f, 0.f, 0.f};
  int fb = t * 4;
  for (int base = start; base < end; base += 256) {
    int ce = base + t;
    if (ce < end) {
      int s = es_src[ce];
      if ((unsigned)s >= NODES) { atomicOr(diag, 1); s = 0; }
      ssrc[t] = s;
      nrm[t] = dinv[s] * dd;
    }
    __syncthreads();
    int cnt2 = end - base; if (cnt2 > 256) cnt2 = 256;
    if (t < 195) {
      for (int ce2 = 0; ce2 < cnt2; ++ce2) {
        int ss = ssrc[ce2];
        float nv = nrm[ce2];
        uint2 u = *(const uint2*)(h2 + (size_t)ss * HP + fb);
        acc[0] += nv * us2f((unsigned short)(u.x & 0xffffu));
        acc[1] += nv * us2f((unsigned short)(u.x >> 16));
        acc[2] += nv * us2f((unsigned short)(u.y & 0xffffu));
        acc[3] += nv * us2f((unsigned short)(u.y >> 16));
      }
    }
    __syncthreads();
  }
  if (t < 196) {
    if (t < 195 && (nanf_(acc[0]) || nanf_(acc[3]))) atomicOr(diag, 16);
    unsigned short o[4];
#pragma unroll
    for (int k = 0; k < 4; ++k) {
      int f = fb + k;
      float v = 0.f;
      if (f < HIDD) v = fmaxf(acc[k] + ldany(gcn_b, f, mode), 0.f);
      o[k] = f2us(v);
    }
    uint2 pack;
    __builtin_memcpy(&pack, o, 8);
    *(uint2*)(x2b + (size_t)d * HP + fb) = pack;
  }
}

// ---------- segment pool: xg_pool[b][f] = sum_{d in segment} x2b[d][f]
__global__ __launch_bounds__(256) void k_pool(const bf16* x2b, const int* bstart,
                                              float* xg_pool) {
  int b = blockIdx.x, t = threadIdx.x;
  if (t >= 195) return;
  int r0 = bstart[b], r1 = bstart[b + 1];
  int fb = t * 4;
  float4 acc = {0.f, 0.f, 0.f, 0.f};
  for (int r = r0; r < r1; ++r) {
    uint2 u = *(const uint2*)(x2b + (size_t)r * HP + fb);
    acc.x += us2f((unsigned short)(u.x & 0xffffu));
    acc.y += us2f((unsigned short)(u.x >> 16));
    acc.z += us2f((unsigned short)(u.y & 0xffffu));
    acc.w += us2f((unsigned short)(u.y >> 16));
  }
  *(float4*)&xg_pool[(size_t)b * HIDD + fb] = acc;
}

// ---------- conv via LUT -> bf16 output
__global__ __launch_bounds__(256) void k_conv(const int* target, const float* Mtab,
                                              const void* cb, bf16* c, int* diag) {
  int b = blockIdx.y, tc = blockIdx.x, t = threadIdx.x;
  __shared__ float Mt[NFC * KSZ * VOCS];
  __shared__ int tg[256 + KSZ - 1];
  int mode = diag[1];
  for (int e = t; e < NFC * KSZ * VOCS; e += 256) Mt[e] = Mtab[e];
  int tbase = tc * 256;
  for (int e = t; e < 256 + KSZ - 1; e += 256) {
    int p = tbase + e;
    int tv = (p < SEQL) ? target[b * SEQL + p] : 0;
    if ((unsigned)tv >= VOCS) { atomicOr(diag, 8192); tv = 0; }
    tg[e] = tv;
  }
  __syncthreads();
  int tt = tbase + t;
  if (tt >= COUT) return;
  float acc[NFC];
#pragma unroll
  for (int o = 0; o < NFC; ++o) acc[o] = 0.f;
#pragma unroll
  for (int k = 0; k < KSZ; ++k) {
    int v = tg[t + k];
    const float* Mk = &Mt[k * VOCS + v];
#pragma unroll
    for (int o = 0; o < NFC; ++o) acc[o] += Mk[o * KSZ * VOCS];
  }
  if (nanf_(acc[0])) atomicOr(diag, 4096);
#pragma unroll
  for (int o = 0; o < NFC; ++o)
    c[(size_t)b * KFXT + o * COUT + tt] = __float2bfloat16(acc[o] + ldany(cb, o, mode));
}

// ---------- final 128->1 + diag encoding (applies relu to xf4 pre-activations)
__global__ __launch_bounds__(64) void k_out(const float* xf4, const void* o_W,
                                            const void* o_b, void* outp, const int* diag) {
  int b = blockIdx.x, lane = threadIdx.x;
  int mode = diag[1];
  float a0 = fmaxf(xf4[b * 128 + lane], 0.f);
  float a1 = fmaxf(xf4[b * 128 + 64 + lane], 0.f);
  float v = a0 * ldany(o_W, lane, mode) + a1 * ldany(o_W, 64 + lane, mode);
  for (int off = 32; off; off >>= 1) v += __shfl_down(v, off, 64);
  if (lane == 0) {
    float r = v + ldany(o_b, 0, mode);
    int dg = diag[0];
    if (dg) r = 256.f * (1 + mode) + 8.f * (float)(__ffs(dg) - 1);
    else if (nanf_(r)) r = 200.f + 100.f * mode;
    if (mode) ((float*)outp)[b] = r;
    else ((bf16*)outp)[b] = __float2bfloat16(r);
  }
}

extern "C" void kernel_launch(void* const* d_in, const int* in_sizes, int n_in,
                              void* d_out, int out_size, void* d_ws, size_t ws_size,
                              hipStream_t stream) {
  const void* x       = d_in[0];
  const int*  ei      = (const int*)d_in[1];
  const int*  batch   = (const int*)d_in[2];
  const int*  target  = (const int*)d_in[3];
  const void* gat_W   = d_in[4];
  const void* a_src   = d_in[5];
  const void* a_dst   = d_in[6];
  const void* gat_b   = d_in[7];
  const void* gcn_W   = d_in[8];
  const void* gcn_b   = d_in[9];
  const void* fcg1_W  = d_in[10];
  const void* fcg1_b  = d_in[11];
  const void* fcg2_W  = d_in[12];
  const void* fcg2_b  = d_in[13];
  const void* emb     = d_in[14];
  const void* cW      = d_in[15];
  const void* cb      = d_in[16];
  const void* fxt_W   = d_in[17];
  const void* fxt_b   = d_in[18];
  const void* f1_W    = d_in[19];
  const void* f1_b    = d_in[20];
  const void* f2_W    = d_in[21];
  const void* f2_b    = d_in[22];
  const void* f3_W    = d_in[23];
  const void* f3_b    = d_in[24];
  const void* f4_W    = d_in[25];
  const void* f4_b    = d_in[26];
  const void* o_W     = d_in[27];
  const void* o_b     = d_in[28];

  char* w = (char*)d_ws;
  size_t off = 0;
  auto alloc = [&](size_t bytes) -> void* {
    void* p = w + off;
    off = (off + bytes + 255) & ~(size_t)255;
    return p;
  };
  bf16*  h_buf   = (bf16*)alloc((size_t)NODES * HP * 2);    // h, then h2 (stride HP)
  bf16*  x1p     = (bf16*)alloc((size_t)MPAD * KP2 * 2);    // x1 padded; REUSED as x2b
  bf16*  xpad    = (bf16*)alloc((size_t)MPAD * KP1 * 2);
  bf16*  gatWt   = (bf16*)alloc((size_t)NPADB * KP1 * 2);
  bf16*  gcnWt   = (bf16*)alloc((size_t)NPADB * KP2 * 2);
  float* a_s     = (float*)alloc((size_t)NODES * HEADS * 4);
  float* a_d     = (float*)alloc((size_t)NODES * HEADS * 4);
  float* Ws      = (float*)alloc(FD * HEADS * 4);
  float* Wd      = (float*)alloc(FD * HEADS * 4);
  float* Mtab    = (float*)alloc(NFC * KSZ * VOCS * 4);
  int*   rowst   = (int*)alloc((NODES + 1) * 4);
  float* dinv    = (float*)alloc(NODES * 4);
  int*   bstart  = (int*)alloc((GB + 1) * 4);
  bf16*  c_buf   = (bf16*)alloc((size_t)GB * KFXT * 2);
  // ---- contiguous zero-initialized region (single memset) ----
  size_t zoff = off;
  int*   cnt     = (int*)alloc(NODES * 4);
  int*   cur     = (int*)alloc(NODES * 4);
  int*   es_src  = (int*)alloc((size_t)ETOT * 4);
  float* xg_pool = (float*)alloc((size_t)GB * HIDD * 4);
  float* xg1     = (float*)alloc((size_t)GB * 1500 * 4);
  float* xc      = (float*)alloc((size_t)GB * 256 * 4);
  float* xf1     = (float*)alloc((size_t)GB * 1024 * 4);
  float* xf2     = (float*)alloc((size_t)GB * 512 * 4);
  float* xf3     = (float*)alloc((size_t)GB * 256 * 4);
  float* xf4     = (float*)alloc((size_t)GB * 128 * 4);
  int*   diag    = (int*)alloc(2 * 4);
  size_t zlen = off - zoff;

  bf16* x2b = x1p;  // x1p dead after gemm2; reuse for x2 rows (stride HP)

  hipMemsetAsync(w + zoff, 0, zlen, stream);

  k_detect<<<1, 256, 0, stream>>>(x, diag);

  k_pad_x<<<(MPAD * KP1 + 255) / 256, 256, 0, stream>>>(x, xpad, diag);
  k_tr_gatw<<<(NPADB * KP1 + 255) / 256, 256, 0, stream>>>(gat_W, gatWt, diag);
  k_tr_gcnw<<<(NPADB * KP2 + 255) / 256, 256, 0, stream>>>(gcn_W, gcnWt, diag);
  k_zero_x1pad<<<((MPAD - NODES) * KP2 + 255) / 256, 256, 0, stream>>>(x1p);

  k_prep_ws<<<(FD * HEADS + 255) / 256, 256, 0, stream>>>(gat_W, a_src, a_dst, Ws, Wd, diag);
  k_prep_mtab<<<(NFC * KSZ * VOCS + 255) / 256, 256, 0, stream>>>(emb, cW, Mtab, diag);

  // h = x @ gat_W   (MFMA, row stride HP)
  k_gemm_mfma<<<dim3(NPADB / NT, MPAD / MT), 256, 0, stream>>>(
      xpad, KP1, gatWt, KP1, h_buf, HP, HP, NODES, KP1);
  k_asd<<<(NODES + 255) / 256, 256, 0, stream>>>(x, Ws, Wd, a_s, a_d, diag);

  // CSR + batch segments
  k_count<<<(ETOT + 255) / 256, 256, 0, stream>>>(ei, cnt, diag);
  k_scan<<<1, 1024, 0, stream>>>(cnt, rowst);
  k_dinv<<<(NODES + 255) / 256, 256, 0, stream>>>(cnt, dinv);
  k_scatter<<<(ETOT + 255) / 256, 256, 0, stream>>>(ei, rowst, cur, es_src, diag);
  k_csrchk<<<(NODES + 255) / 256, 256, 0, stream>>>(cnt, cur, rowst, diag);
  k_bseg<<<(NODES + 255) / 256, 256, 0, stream>>>(batch, bstart, diag);

  k_gat<<<NODES, 256, 0, stream>>>(es_src, rowst, a_s, a_d, h_buf, gat_b, x1p, diag);

  // h2 = x1 @ gcn_W  (MFMA; h_buf reused, stride HP)
  k_gemm_mfma<<<dim3(NPADB / NT, MPAD / MT), 256, 0, stream>>>(
      x1p, KP2, gcnWt, KP2, h_buf, HP, HP, NODES, KP2);

  // GCN agg -> x2b (no atomics; x1p region reused), then sorted-segment pool
  k_gcn<<<NODES, 256, 0, stream>>>(es_src, rowst, dinv, h_buf, gcn_b, x2b, diag);
  k_pool<<<GB, 256, 0, stream>>>(x2b, bstart, xg_pool);

  k_conv<<<dim3(4, GB), 256, 0, stream>>>(target, Mtab, cb, c_buf, diag);

  // MLP chain via MFMA; pre-activation outputs, relu applied on consumer A-load
  k_mlp_mfma<<<dim3(24, 4), 256, 0, stream>>>(xg_pool, HIDD, fcg1_W, fcg1_b,
                                              xg1, 1500, 0, GB, 1500, HIDD, 4, 0, 0, diag);
  k_mlp_mfma<<<dim3(2, 16), 256, 0, stream>>>(xg1, 1500, fcg2_W, fcg2_b,
                                              xc, 256, 0, GB, 128, 1500, 16, 1, 0, diag);
  k_mlp_mfma<<<dim3(2, 64), 256, 0, stream>>>(c_buf, KFXT, fxt_W, fxt_b,
                                              xc, 256, 128, GB, 128, KFXT, 64, 0, 1, diag);
  k_mlp_mfma<<<dim3(16, 4), 256, 0, stream>>>(xc, 256, f1_W, f1_b,
                                              xf1, 1024, 0, GB, 1024, 256, 4, 0, 0, diag);
  k_mlp_mfma<<<dim3(8, 8), 256, 0, stream>>>(xf1, 1024, f2_W, f2_b,
                                             xf2, 512, 0, GB, 512, 1024, 8, 1, 0, diag);
  k_mlp_mfma<<<dim3(4, 8), 256, 0, stream>>>(xf2, 512, f3_W, f3_b,
                                             xf3, 256, 0, GB, 256, 512, 8, 1, 0, diag);
  k_mlp_mfma<<<dim3(2, 8), 256, 0, stream>>>(xf3, 256, f4_W, f4_b,
                                             xf4, 128, 0, GB, 128, 256, 8, 1, 0, diag);
  k_out<<<GB, 64, 0, stream>>>(xf4, o_W, o_b, d_out, diag);
}